// Round 5
// baseline (277.935 us; speedup 1.0000x reference)
//
#include <hip/hip_runtime.h>

#define B_ 128
#define N_ 64
#define T_ 1000
#define H_ 16

// ---------------- A: energy[b,i] = var(x[b,0,i,:], ddof=1) ----------------
__global__ __launch_bounds__(256) void k_energy(const float* __restrict__ x, float* __restrict__ energy) {
    int row = blockIdx.x;                       // b*64 + i
    const float* xr = x + (size_t)row * T_;
    float s = 0.f, s2 = 0.f;
    for (int t4 = threadIdx.x; t4 < 250; t4 += 256) {
        float4 v = ((const float4*)xr)[t4];
        s += v.x + v.y + v.z + v.w;
        s2 += v.x*v.x + v.y*v.y + v.z*v.z + v.w*v.w;
    }
    __shared__ float r1[256], r2[256];
    r1[threadIdx.x] = s; r2[threadIdx.x] = s2;
    __syncthreads();
    for (int off = 128; off > 0; off >>= 1) {
        if (threadIdx.x < off) {
            r1[threadIdx.x] += r1[threadIdx.x + off];
            r2[threadIdx.x] += r2[threadIdx.x + off];
        }
        __syncthreads();
    }
    if (threadIdx.x == 0) {
        float S = r1[0], S2 = r2[0];
        energy[row] = (S2 - S * S / (float)T_) / (float)(T_ - 1);
    }
}

// ---------------- B: attn + diag-mask + softmax -> w (written to d_out) ----
__global__ void k_attn_softmax(const float* __restrict__ energy,
                               const float* __restrict__ q_w, const float* __restrict__ q_b,
                               const float* __restrict__ k_w, const float* __restrict__ k_b,
                               float* __restrict__ wout) {
    int row = blockIdx.x;                       // b*64 + i
    int b = row >> 6, i = row & 63;
    int j = threadIdx.x;                        // 64 threads
    float ei = energy[b * 64 + i];
    float ej = energy[b * 64 + j];
    float a = 0.f;
    #pragma unroll
    for (int h = 0; h < H_; ++h)
        a += (ei * q_w[h] + q_b[h]) * (ej * k_w[h] + k_b[h]);
    a *= 0.25f;                                 // H^(-1/2), H=16
    if (j == i) a = -1e9f;
    float m = a;
    #pragma unroll
    for (int mask = 32; mask; mask >>= 1) m = fmaxf(m, __shfl_xor(m, mask));
    float p = __expf(a - m);
    float s = p;
    #pragma unroll
    for (int mask = 32; mask; mask >>= 1) s += __shfl_xor(s, mask);
    wout[(size_t)row * 64 + j] = p / s;
}

// ---------------- C: z_gcn = w @ xs + x  (register-tiled 8x4) --------------
#define ZTC 128
__global__ __launch_bounds__(256) void k_zgcn(const float* __restrict__ wmat,
        const float* __restrict__ x, float* __restrict__ zg) {
    int b = blockIdx.y;
    int t0 = blockIdx.x * ZTC;                  // 8 chunks: 0,128,...,896
    __shared__ __attribute__((aligned(16))) float wsh[64 * 64];
    __shared__ __attribute__((aligned(16))) float xs[64][ZTC];
    const float4* wb4 = (const float4*)(wmat + (size_t)b * 4096);
    float4* wsh4 = (float4*)wsh;
    for (int i = threadIdx.x; i < 1024; i += 256) wsh4[i] = wb4[i];
    const float* xb = x + (size_t)b * 64 * T_;
    for (int i = threadIdx.x; i < 2048; i += 256) {
        int jj = i >> 5;                        // row (32 float4 per row)
        int c4 = i & 31;
        int tt = t0 + c4 * 4;
        float4 val;
        if (tt + 3 < T_) val = *(const float4*)(xb + jj * T_ + tt);
        else {
            val.x = (tt     < T_) ? xb[jj * T_ + tt]     : 0.f;
            val.y = (tt + 1 < T_) ? xb[jj * T_ + tt + 1] : 0.f;
            val.z = (tt + 2 < T_) ? xb[jj * T_ + tt + 2] : 0.f;
            val.w = (tt + 3 < T_) ? xb[jj * T_ + tt + 3] : 0.f;
        }
        *(float4*)&xs[jj][c4 * 4] = val;
    }
    __syncthreads();
    int gi = threadIdx.x >> 5;                  // 8 ii-groups
    int gt = threadIdx.x & 31;                  // 32 tt-groups
    int ii0 = gi * 8, tt0 = gt * 4;
    float4 acc[8];
    #pragma unroll
    for (int r = 0; r < 8; ++r) acc[r] = float4{0.f, 0.f, 0.f, 0.f};
    for (int jj = 0; jj < 64; ++jj) {
        float4 xv = *(const float4*)&xs[jj][tt0];
        #pragma unroll
        for (int r = 0; r < 8; ++r) {
            float wv = wsh[(ii0 + r) * 64 + jj];
            acc[r].x += wv * xv.x; acc[r].y += wv * xv.y;
            acc[r].z += wv * xv.z; acc[r].w += wv * xv.w;
        }
    }
    int tt = t0 + tt0;
    #pragma unroll
    for (int r = 0; r < 8; ++r) {
        float4 res = *(const float4*)&xs[ii0 + r][tt0];
        acc[r].x += res.x; acc[r].y += res.y; acc[r].z += res.z; acc[r].w += res.w;
        float* dst = zg + (size_t)b * 64 * T_ + (size_t)(ii0 + r) * T_;
        if (tt + 3 < T_) {
            *(float4*)(dst + tt) = acc[r];
        } else {
            if (tt     < T_) dst[tt]     = acc[r].x;
            if (tt + 1 < T_) dst[tt + 1] = acc[r].y;
            if (tt + 2 < T_) dst[tt + 2] = acc[r].z;
            if (tt + 3 < T_) dst[tt + 3] = acc[r].w;
        }
    }
}

// ---------------- D1: autocorr lags 0..14 + total sum (LDS-staged) --------
// stats[0..14] = A[d] = sum_rows sum_i z[i]*z[i+d];  stats[15] = SA = sum z
// block: 128 threads = 16 rows x 8 chunks of 125; LDS = 16 rows x 1014 f32
__global__ __launch_bounds__(128) void k_autocorr(const float* __restrict__ zg, double* __restrict__ stats) {
    __shared__ float rows[16][1014];            // 64896 B (tail 1000..1013 zeroed)
    int row0 = blockIdx.x * 16;
    for (int idx = threadIdx.x; idx < 16 * 1014; idx += 128) {
        int rr = idx / 1014, j = idx - rr * 1014;
        rows[rr][j] = (j < T_) ? zg[(size_t)(row0 + rr) * T_ + j] : 0.f;
    }
    __syncthreads();
    int r = threadIdx.x >> 3, q = threadIdx.x & 7;
    const float* p = &rows[r][0];
    int t = q * 125;
    float w0=p[t+0], w1=p[t+1], w2=p[t+2], w3=p[t+3], w4=p[t+4], w5=p[t+5], w6=p[t+6],
          w7=p[t+7], w8=p[t+8], w9=p[t+9], w10=p[t+10], w11=p[t+11], w12=p[t+12], w13=p[t+13], w14;
    float a0=0.f,a1=0.f,a2=0.f,a3=0.f,a4=0.f,a5=0.f,a6=0.f,a7=0.f,a8=0.f,a9=0.f,
          a10=0.f,a11=0.f,a12=0.f,a13=0.f,a14=0.f, s1=0.f;
    #define ASTEP(wA,wB,wC,wD,wE,wF,wG,wH,wI,wJ,wK,wL,wM,wN,wO, off) { \
        wO = p[t + (off) + 14]; \
        s1 += wA; \
        a0  = fmaf(wA,wA,a0);  a1  = fmaf(wA,wB,a1);  a2  = fmaf(wA,wC,a2);  \
        a3  = fmaf(wA,wD,a3);  a4  = fmaf(wA,wE,a4);  a5  = fmaf(wA,wF,a5);  \
        a6  = fmaf(wA,wG,a6);  a7  = fmaf(wA,wH,a7);  a8  = fmaf(wA,wI,a8);  \
        a9  = fmaf(wA,wJ,a9);  a10 = fmaf(wA,wK,a10); a11 = fmaf(wA,wL,a11); \
        a12 = fmaf(wA,wM,a12); a13 = fmaf(wA,wN,a13); a14 = fmaf(wA,wO,a14); }
    #define AR0(o)  ASTEP(w0,w1,w2,w3,w4,w5,w6,w7,w8,w9,w10,w11,w12,w13,w14, o)
    #define AR1(o)  ASTEP(w1,w2,w3,w4,w5,w6,w7,w8,w9,w10,w11,w12,w13,w14,w0, o)
    #define AR2(o)  ASTEP(w2,w3,w4,w5,w6,w7,w8,w9,w10,w11,w12,w13,w14,w0,w1, o)
    #define AR3(o)  ASTEP(w3,w4,w5,w6,w7,w8,w9,w10,w11,w12,w13,w14,w0,w1,w2, o)
    #define AR4(o)  ASTEP(w4,w5,w6,w7,w8,w9,w10,w11,w12,w13,w14,w0,w1,w2,w3, o)
    #define AR5(o)  ASTEP(w5,w6,w7,w8,w9,w10,w11,w12,w13,w14,w0,w1,w2,w3,w4, o)
    #define AR6(o)  ASTEP(w6,w7,w8,w9,w10,w11,w12,w13,w14,w0,w1,w2,w3,w4,w5, o)
    #define AR7(o)  ASTEP(w7,w8,w9,w10,w11,w12,w13,w14,w0,w1,w2,w3,w4,w5,w6, o)
    #define AR8(o)  ASTEP(w8,w9,w10,w11,w12,w13,w14,w0,w1,w2,w3,w4,w5,w6,w7, o)
    #define AR9(o)  ASTEP(w9,w10,w11,w12,w13,w14,w0,w1,w2,w3,w4,w5,w6,w7,w8, o)
    #define AR10(o) ASTEP(w10,w11,w12,w13,w14,w0,w1,w2,w3,w4,w5,w6,w7,w8,w9, o)
    #define AR11(o) ASTEP(w11,w12,w13,w14,w0,w1,w2,w3,w4,w5,w6,w7,w8,w9,w10, o)
    #define AR12(o) ASTEP(w12,w13,w14,w0,w1,w2,w3,w4,w5,w6,w7,w8,w9,w10,w11, o)
    #define AR13(o) ASTEP(w13,w14,w0,w1,w2,w3,w4,w5,w6,w7,w8,w9,w10,w11,w12, o)
    #define AR14(o) ASTEP(w14,w0,w1,w2,w3,w4,w5,w6,w7,w8,w9,w10,w11,w12,w13, o)
    for (int mi = 0; mi < 8; ++mi) {            // 8*15 = 120 steps
        AR0(0) AR1(1) AR2(2) AR3(3) AR4(4) AR5(5) AR6(6) AR7(7)
        AR8(8) AR9(9) AR10(10) AR11(11) AR12(12) AR13(13) AR14(14)
        t += 15;
    }
    AR0(0) AR1(1) AR2(2) AR3(3) AR4(4)          // tail -> 125 steps
    #undef ASTEP
    __syncthreads();
    float* red = &rows[0][0];                   // reuse LDS: 128 x 17 floats
    int tid = threadIdx.x;
    red[tid*17+0]=a0;  red[tid*17+1]=a1;  red[tid*17+2]=a2;  red[tid*17+3]=a3;
    red[tid*17+4]=a4;  red[tid*17+5]=a5;  red[tid*17+6]=a6;  red[tid*17+7]=a7;
    red[tid*17+8]=a8;  red[tid*17+9]=a9;  red[tid*17+10]=a10; red[tid*17+11]=a11;
    red[tid*17+12]=a12; red[tid*17+13]=a13; red[tid*17+14]=a14; red[tid*17+15]=s1;
    __syncthreads();
    for (int off = 64; off > 0; off >>= 1) {
        if (tid < off)
            for (int k = 0; k < 16; ++k) red[tid*17+k] += red[(tid+off)*17+k];
        __syncthreads();
    }
    if (tid < 16) atomicAdd(&stats[tid], (double)red[tid]);
}

// ---------------- D2: boundary corrections — one stat per block ------------
__global__ __launch_bounds__(256) void k_edges(const float* __restrict__ zg, double* __restrict__ stats) {
    int v = blockIdx.x;                         // 0..146, uniform per block
    int mode, ia, ib;
    if (v < 105) { mode = 0; ia = v / 15; ib = ia + (v % 15); }          // head pair
    else if (v < 133) {
        int idx = v - 105; int i = 0, len = 7;
        while (idx >= len) { idx -= len; ++i; --len; }
        mode = 2; ia = i; ib = i + idx;                                   // tail-local idx
    }
    else if (v < 140) { mode = 1; ia = 0; ib = v - 133; }                 // prefix head
    else { mode = 3; ia = v - 140; ib = 6; }                              // suffix tail-local
    double acc = 0.0;
    for (int it = 0; it < 32; ++it) {
        int row = it * 256 + threadIdx.x;
        const float* zr = zg + (size_t)row * T_;
        float val;
        if (mode == 0)      val = zr[ia] * zr[ib];
        else if (mode == 2) val = zr[993 + ia] * zr[993 + ib];
        else if (mode == 1) { val = 0.f; for (int i = ia; i <= ib; ++i) val += zr[i]; }
        else                { val = 0.f; for (int i = ia; i <= ib; ++i) val += zr[993 + i]; }
        acc += (double)val;
    }
    __shared__ double red[256];
    red[threadIdx.x] = acc;
    __syncthreads();
    for (int off = 128; off > 0; off >>= 1) {
        if (threadIdx.x < off) red[threadIdx.x] += red[threadIdx.x + off];
        __syncthreads();
    }
    if (threadIdx.x == 0) stats[16 + v] = red[0];
}

// ---------------- E: finalize BN -> folded taps + shift --------------------
__global__ void k_finalize2(const double* __restrict__ stats, const float* __restrict__ conv_w,
                            const float* __restrict__ gamma, const float* __restrict__ beta,
                            float* __restrict__ scsh) {
    int h = threadIdx.x;
    if (h >= 16) return;
    const double M = (double)(B_ * N_) * (double)T_;
    double w[15];
    for (int k = 0; k < 15; ++k) w[k] = (double)conv_w[h * 15 + k];
    double SA = stats[15];
    const double* HP  = stats + 16;
    const double* TP  = stats + 16 + 105;
    const double* PRE = stats + 16 + 133;
    const double* SUF = stats + 16 + 140;
    double so = 0.0;
    for (int k = 0; k < 15; ++k) {
        double U = SA;
        if (k < 7)      U -= SUF[k];
        else if (k > 7) U -= PRE[k - 8];
        so += w[k] * U;
    }
    double mean_o = so / M;
    double q = 0.0;
    for (int k = 0; k < 15; ++k)
    for (int k2 = 0; k2 < 15; ++k2) {
        int a = (k < k2) ? k : k2;
        int d = (k < k2) ? (k2 - k) : (k - k2);
        double G = stats[d];
        if (a >= 8)
            for (int i = 0; i <= a - 8; ++i) G -= HP[i * 15 + d];
        if (a + d <= 6)
            for (int i = a + 993; i <= 999 - d; ++i) {
                int ip = i - 993;
                G -= TP[ip * 7 - ip * (ip - 1) / 2 + d];
            }
        q += w[k] * w[k2] * G;
    }
    double var = q / M - mean_o * mean_o;
    double sc = (double)gamma[h] / sqrt(var + 1e-5);
    scsh[240 + h] = (float)((double)beta[h] - mean_o * sc);
    for (int k = 0; k < 15; ++k) scsh[h * 15 + k] = (float)(w[k] * sc);
}

// ------- F: conv(+BN folded) + ELU + LIF scan, named-register window -------
// 16 rows x 16 ch per block; T in 8 chunks of 125; LDS 2 x 16 x 140 floats.
__global__ __launch_bounds__(256, 2) void k_scan(const float* __restrict__ zg,
        const float* __restrict__ scsh, float* __restrict__ zfeat) {
    __shared__ float buf[2][16][140];
    int h = threadIdx.x & 15, r = threadIdx.x >> 4;
    int row0 = blockIdx.x * 16;
    float c0 = scsh[h*15+0],  c1 = scsh[h*15+1],  c2 = scsh[h*15+2],  c3 = scsh[h*15+3];
    float c4 = scsh[h*15+4],  c5 = scsh[h*15+5],  c6 = scsh[h*15+6],  c7 = scsh[h*15+7];
    float c8 = scsh[h*15+8],  c9 = scsh[h*15+9],  c10 = scsh[h*15+10], c11 = scsh[h*15+11];
    float c12 = scsh[h*15+12], c13 = scsh[h*15+13], c14 = scsh[h*15+14];
    float sh = scsh[240 + h];

    #define STAGE(cc, db) { \
        int g0 = 125 * (cc) - 7; \
        for (int idx = threadIdx.x; idx < 16 * 139; idx += 256) { \
            int rr = idx / 139, u = idx - rr * 139; \
            int g = g0 + u; \
            float val = 0.f; \
            if (g >= 0 && g < T_) val = zg[(size_t)(row0 + rr) * T_ + g]; \
            buf[db][rr][u] = val; \
        } }

    float v = 0.f, cnt = 0.f;
    STAGE(0, 0)
    __syncthreads();
    for (int c = 0; c < 8; ++c) {
        if (c < 7) STAGE(c + 1, (c + 1) & 1)
        const float* p = &buf[c & 1][r][0];
        float w0=p[0], w1=p[1], w2=p[2], w3=p[3], w4=p[4], w5=p[5], w6=p[6],
              w7=p[7], w8=p[8], w9=p[9], w10=p[10], w11=p[11], w12=p[12], w13=p[13], w14;
        int t = 0;
        #define STEP(wA,wB,wC,wD,wE,wF,wG,wH,wI,wJ,wK,wL,wM,wN,wO, off) { \
            wO = p[t + (off) + 14]; \
            float o0 = fmaf(c0,wA, fmaf(c3,wD, fmaf(c6,wG, fmaf(c9,wJ, fmaf(c12,wM, sh))))); \
            float o1 = fmaf(c1,wB, fmaf(c4,wE, fmaf(c7,wH, fmaf(c10,wK, c13*wN)))); \
            float o2 = fmaf(c2,wC, fmaf(c5,wF, fmaf(c8,wI, fmaf(c11,wL, c14*wO)))); \
            float zf = (o0 + o1) + o2; \
            float xm = fminf(zf, 0.f), xp = fmaxf(zf, 0.f); \
            float ea = __expf(xm); \
            v = fmaf(0.5f, v, xp) + ea - 1.f; \
            float sp = (v > 0.5f) ? 1.f : 0.f; \
            cnt += sp; v = fmaf(-0.5f, sp, v); }
        #define R0(o)  STEP(w0,w1,w2,w3,w4,w5,w6,w7,w8,w9,w10,w11,w12,w13,w14, o)
        #define R1(o)  STEP(w1,w2,w3,w4,w5,w6,w7,w8,w9,w10,w11,w12,w13,w14,w0, o)
        #define R2(o)  STEP(w2,w3,w4,w5,w6,w7,w8,w9,w10,w11,w12,w13,w14,w0,w1, o)
        #define R3(o)  STEP(w3,w4,w5,w6,w7,w8,w9,w10,w11,w12,w13,w14,w0,w1,w2, o)
        #define R4(o)  STEP(w4,w5,w6,w7,w8,w9,w10,w11,w12,w13,w14,w0,w1,w2,w3, o)
        #define R5(o)  STEP(w5,w6,w7,w8,w9,w10,w11,w12,w13,w14,w0,w1,w2,w3,w4, o)
        #define R6(o)  STEP(w6,w7,w8,w9,w10,w11,w12,w13,w14,w0,w1,w2,w3,w4,w5, o)
        #define R7(o)  STEP(w7,w8,w9,w10,w11,w12,w13,w14,w0,w1,w2,w3,w4,w5,w6, o)
        #define R8(o)  STEP(w8,w9,w10,w11,w12,w13,w14,w0,w1,w2,w3,w4,w5,w6,w7, o)
        #define R9(o)  STEP(w9,w10,w11,w12,w13,w14,w0,w1,w2,w3,w4,w5,w6,w7,w8, o)
        #define R10(o) STEP(w10,w11,w12,w13,w14,w0,w1,w2,w3,w4,w5,w6,w7,w8,w9, o)
        #define R11(o) STEP(w11,w12,w13,w14,w0,w1,w2,w3,w4,w5,w6,w7,w8,w9,w10, o)
        #define R12(o) STEP(w12,w13,w14,w0,w1,w2,w3,w4,w5,w6,w7,w8,w9,w10,w11, o)
        #define R13(o) STEP(w13,w14,w0,w1,w2,w3,w4,w5,w6,w7,w8,w9,w10,w11,w12, o)
        #define R14(o) STEP(w14,w0,w1,w2,w3,w4,w5,w6,w7,w8,w9,w10,w11,w12,w13, o)
        for (int mi = 0; mi < 8; ++mi) {        // 8*15 = 120 steps
            R0(0) R1(1) R2(2) R3(3) R4(4) R5(5) R6(6) R7(7)
            R8(8) R9(9) R10(10) R11(11) R12(12) R13(13) R14(14)
            t += 15;
        }
        R0(0) R1(1) R2(2) R3(3) R4(4)           // tail -> 125 steps
        #undef STEP
        #undef R0
        #undef R1
        #undef R2
        #undef R3
        #undef R4
        #undef R5
        #undef R6
        #undef R7
        #undef R8
        #undef R9
        #undef R10
        #undef R11
        #undef R12
        #undef R13
        #undef R14
        __syncthreads();
    }
    #undef STAGE
    int row = row0 + r;
    int b = row >> 6, i = row & 63;
    zfeat[(size_t)b * 1024 + h * 64 + i] = cnt * (1.0f / (float)T_);
}

// ---------------- G: logits = z_feat @ fc_w.T + fc_b -----------------------
__global__ __launch_bounds__(256) void k_fc(const float* __restrict__ zfeat, const float* __restrict__ fc_w,
                     const float* __restrict__ fc_b, float* __restrict__ logits) {
    int b = blockIdx.x;
    const float* zf = zfeat + (size_t)b * 1024;
    float a0 = 0.f, a1 = 0.f, a2 = 0.f, a3 = 0.f;
    for (int f = threadIdx.x; f < 1024; f += 256) {
        float z = zf[f];
        a0 += z * fc_w[f];
        a1 += z * fc_w[1024 + f];
        a2 += z * fc_w[2048 + f];
        a3 += z * fc_w[3072 + f];
    }
    __shared__ float red[4][256];
    red[0][threadIdx.x] = a0; red[1][threadIdx.x] = a1;
    red[2][threadIdx.x] = a2; red[3][threadIdx.x] = a3;
    __syncthreads();
    for (int off = 128; off > 0; off >>= 1) {
        if (threadIdx.x < off) {
            red[0][threadIdx.x] += red[0][threadIdx.x + off];
            red[1][threadIdx.x] += red[1][threadIdx.x + off];
            red[2][threadIdx.x] += red[2][threadIdx.x + off];
            red[3][threadIdx.x] += red[3][threadIdx.x + off];
        }
        __syncthreads();
    }
    if (threadIdx.x < 4) logits[b * 4 + threadIdx.x] = red[threadIdx.x][0] + fc_b[threadIdx.x];
}

extern "C" void kernel_launch(void* const* d_in, const int* in_sizes, int n_in,
                              void* d_out, int out_size, void* d_ws, size_t ws_size,
                              hipStream_t stream) {
    (void)in_sizes; (void)n_in; (void)out_size; (void)ws_size;
    const float* x      = (const float*)d_in[0];
    const float* q_w    = (const float*)d_in[1];
    const float* q_b    = (const float*)d_in[2];
    const float* k_w    = (const float*)d_in[3];
    const float* k_b    = (const float*)d_in[4];
    const float* conv_w = (const float*)d_in[5];
    const float* bn_g   = (const float*)d_in[7];
    const float* bn_b   = (const float*)d_in[8];
    const float* fc_w   = (const float*)d_in[9];
    const float* fc_b   = (const float*)d_in[10];

    float* out    = (float*)d_out;
    float* logits = out;                        // 128*4
    float* zfeat  = out + 512;                  // 128*1024
    float* wmat   = out + 512 + 131072;         // 128*64*64

    char* ws      = (char*)d_ws;
    float* energy = (float*)ws;                               // 8192 f32
    float* zg     = (float*)(ws + 32768);                     // 8.192M f32
    double* stats = (double*)(ws + 32768 + 32768000);         // 163 f64
    float* scsh   = (float*)(ws + 32768 + 32768000 + 2048);   // 256 f32

    k_energy<<<B_ * N_, 256, 0, stream>>>(x, energy);
    k_attn_softmax<<<B_ * N_, 64, 0, stream>>>(energy, q_w, q_b, k_w, k_b, wmat);
    k_zgcn<<<dim3(8, B_), 256, 0, stream>>>(wmat, x, zg);
    hipMemsetAsync(stats, 0, 163 * sizeof(double), stream);
    k_autocorr<<<B_ * N_ / 16, 128, 0, stream>>>(zg, stats);
    k_edges<<<147, 256, 0, stream>>>(zg, stats);
    k_finalize2<<<1, 64, 0, stream>>>(stats, conv_w, bn_g, bn_b, scsh);
    k_scan<<<B_ * N_ / 16, 256, 0, stream>>>(zg, scsh, zfeat);
    k_fc<<<B_, 256, 0, stream>>>(zfeat, fc_w, fc_b, logits);
}

// Round 7
// 248.254 us; speedup vs baseline: 1.1196x; 1.1196x over previous
//
#include <hip/hip_runtime.h>

#define B_ 128
#define N_ 64
#define T_ 1000
#define H_ 16

// ---------------- A: energy[b,i] = var(x[b,0,i,:], ddof=1) ----------------
__global__ __launch_bounds__(256) void k_energy(const float* __restrict__ x, float* __restrict__ energy) {
    int row = blockIdx.x;                       // b*64 + i
    const float* xr = x + (size_t)row * T_;
    float s = 0.f, s2 = 0.f;
    for (int t4 = threadIdx.x; t4 < 250; t4 += 256) {
        float4 v = ((const float4*)xr)[t4];
        s += v.x + v.y + v.z + v.w;
        s2 += v.x*v.x + v.y*v.y + v.z*v.z + v.w*v.w;
    }
    __shared__ float r1[256], r2[256];
    r1[threadIdx.x] = s; r2[threadIdx.x] = s2;
    __syncthreads();
    for (int off = 128; off > 0; off >>= 1) {
        if (threadIdx.x < off) {
            r1[threadIdx.x] += r1[threadIdx.x + off];
            r2[threadIdx.x] += r2[threadIdx.x + off];
        }
        __syncthreads();
    }
    if (threadIdx.x == 0) {
        float S = r1[0], S2 = r2[0];
        energy[row] = (S2 - S * S / (float)T_) / (float)(T_ - 1);
    }
}

// ---------------- B: attn + diag-mask + softmax -> w (written to d_out) ----
__global__ void k_attn_softmax(const float* __restrict__ energy,
                               const float* __restrict__ q_w, const float* __restrict__ q_b,
                               const float* __restrict__ k_w, const float* __restrict__ k_b,
                               float* __restrict__ wout) {
    int row = blockIdx.x;                       // b*64 + i
    int b = row >> 6, i = row & 63;
    int j = threadIdx.x;                        // 64 threads
    float ei = energy[b * 64 + i];
    float ej = energy[b * 64 + j];
    float a = 0.f;
    #pragma unroll
    for (int h = 0; h < H_; ++h)
        a += (ei * q_w[h] + q_b[h]) * (ej * k_w[h] + k_b[h]);
    a *= 0.25f;                                 // H^(-1/2), H=16
    if (j == i) a = -1e9f;
    float m = a;
    #pragma unroll
    for (int mask = 32; mask; mask >>= 1) m = fmaxf(m, __shfl_xor(m, mask));
    float p = __expf(a - m);
    float s = p;
    #pragma unroll
    for (int mask = 32; mask; mask >>= 1) s += __shfl_xor(s, mask);
    wout[(size_t)row * 64 + j] = p / s;
}

// ---------------- C: z_gcn = w @ xs + x  (register-tiled 8x4) --------------
#define ZTC 128
__global__ __launch_bounds__(256) void k_zgcn(const float* __restrict__ wmat,
        const float* __restrict__ x, float* __restrict__ zg) {
    int b = blockIdx.y;
    int t0 = blockIdx.x * ZTC;                  // 8 chunks: 0,128,...,896
    __shared__ __attribute__((aligned(16))) float wsh[64 * 64];
    __shared__ __attribute__((aligned(16))) float xs[64][ZTC];
    const float4* wb4 = (const float4*)(wmat + (size_t)b * 4096);
    float4* wsh4 = (float4*)wsh;
    for (int i = threadIdx.x; i < 1024; i += 256) wsh4[i] = wb4[i];
    const float* xb = x + (size_t)b * 64 * T_;
    for (int i = threadIdx.x; i < 2048; i += 256) {
        int jj = i >> 5;                        // row (32 float4 per row)
        int c4 = i & 31;
        int tt = t0 + c4 * 4;
        float4 val;
        if (tt + 3 < T_) val = *(const float4*)(xb + jj * T_ + tt);
        else {
            val.x = (tt     < T_) ? xb[jj * T_ + tt]     : 0.f;
            val.y = (tt + 1 < T_) ? xb[jj * T_ + tt + 1] : 0.f;
            val.z = (tt + 2 < T_) ? xb[jj * T_ + tt + 2] : 0.f;
            val.w = (tt + 3 < T_) ? xb[jj * T_ + tt + 3] : 0.f;
        }
        *(float4*)&xs[jj][c4 * 4] = val;
    }
    __syncthreads();
    int gi = threadIdx.x >> 5;                  // 8 ii-groups
    int gt = threadIdx.x & 31;                  // 32 tt-groups
    int ii0 = gi * 8, tt0 = gt * 4;
    float4 acc[8];
    #pragma unroll
    for (int r = 0; r < 8; ++r) acc[r] = float4{0.f, 0.f, 0.f, 0.f};
    for (int jj = 0; jj < 64; ++jj) {
        float4 xv = *(const float4*)&xs[jj][tt0];
        #pragma unroll
        for (int r = 0; r < 8; ++r) {
            float wv = wsh[(ii0 + r) * 64 + jj];
            acc[r].x += wv * xv.x; acc[r].y += wv * xv.y;
            acc[r].z += wv * xv.z; acc[r].w += wv * xv.w;
        }
    }
    int tt = t0 + tt0;
    #pragma unroll
    for (int r = 0; r < 8; ++r) {
        float4 res = *(const float4*)&xs[ii0 + r][tt0];
        acc[r].x += res.x; acc[r].y += res.y; acc[r].z += res.z; acc[r].w += res.w;
        float* dst = zg + (size_t)b * 64 * T_ + (size_t)(ii0 + r) * T_;
        if (tt + 3 < T_) {
            *(float4*)(dst + tt) = acc[r];
        } else {
            if (tt     < T_) dst[tt]     = acc[r].x;
            if (tt + 1 < T_) dst[tt + 1] = acc[r].y;
            if (tt + 2 < T_) dst[tt + 2] = acc[r].z;
            if (tt + 3 < T_) dst[tt + 3] = acc[r].w;
        }
    }
}

// ---------------- D1: autocorr lags 0..14 + total sum (LDS-staged) --------
// stats[0..14] = A[d] = sum_rows sum_t z[t]*z[t+d];  stats[15] = SA = sum z
// block: 256 threads = 8 rows x 32 spans of 33; LDS zero-padded past T.
__global__ __launch_bounds__(256) void k_autocorr(const float* __restrict__ zg, double* __restrict__ stats) {
    __shared__ float rows[8][1070];             // 34240 B; stride-33 spans, conflict-free
    int row0 = blockIdx.x * 8;
    for (int idx = threadIdx.x; idx < 8 * 1070; idx += 256) {
        int rr = idx / 1070, j = idx - rr * 1070;
        rows[rr][j] = (j < T_) ? zg[(size_t)(row0 + rr) * T_ + j] : 0.f;
    }
    __syncthreads();
    int r = threadIdx.x >> 5, q = threadIdx.x & 31;
    const float* p = &rows[r][0];
    int t = q * 33;                             // spans cover 0..1055 >= 1000, zero-padded
    float w0=p[t+0], w1=p[t+1], w2=p[t+2], w3=p[t+3], w4=p[t+4], w5=p[t+5], w6=p[t+6],
          w7=p[t+7], w8=p[t+8], w9=p[t+9], w10=p[t+10], w11=p[t+11], w12=p[t+12], w13=p[t+13], w14;
    float a0=0.f,a1=0.f,a2=0.f,a3=0.f,a4=0.f,a5=0.f,a6=0.f,a7=0.f,a8=0.f,a9=0.f,
          a10=0.f,a11=0.f,a12=0.f,a13=0.f,a14=0.f, s1=0.f;
    #define ASTEP(wA,wB,wC,wD,wE,wF,wG,wH,wI,wJ,wK,wL,wM,wN,wO, off) { \
        wO = p[t + (off) + 14]; \
        s1 += wA; \
        a0  = fmaf(wA,wA,a0);  a1  = fmaf(wA,wB,a1);  a2  = fmaf(wA,wC,a2);  \
        a3  = fmaf(wA,wD,a3);  a4  = fmaf(wA,wE,a4);  a5  = fmaf(wA,wF,a5);  \
        a6  = fmaf(wA,wG,a6);  a7  = fmaf(wA,wH,a7);  a8  = fmaf(wA,wI,a8);  \
        a9  = fmaf(wA,wJ,a9);  a10 = fmaf(wA,wK,a10); a11 = fmaf(wA,wL,a11); \
        a12 = fmaf(wA,wM,a12); a13 = fmaf(wA,wN,a13); a14 = fmaf(wA,wO,a14); }
    #define AR0(o)  ASTEP(w0,w1,w2,w3,w4,w5,w6,w7,w8,w9,w10,w11,w12,w13,w14, o)
    #define AR1(o)  ASTEP(w1,w2,w3,w4,w5,w6,w7,w8,w9,w10,w11,w12,w13,w14,w0, o)
    #define AR2(o)  ASTEP(w2,w3,w4,w5,w6,w7,w8,w9,w10,w11,w12,w13,w14,w0,w1, o)
    #define AR3(o)  ASTEP(w3,w4,w5,w6,w7,w8,w9,w10,w11,w12,w13,w14,w0,w1,w2, o)
    #define AR4(o)  ASTEP(w4,w5,w6,w7,w8,w9,w10,w11,w12,w13,w14,w0,w1,w2,w3, o)
    #define AR5(o)  ASTEP(w5,w6,w7,w8,w9,w10,w11,w12,w13,w14,w0,w1,w2,w3,w4, o)
    #define AR6(o)  ASTEP(w6,w7,w8,w9,w10,w11,w12,w13,w14,w0,w1,w2,w3,w4,w5, o)
    #define AR7(o)  ASTEP(w7,w8,w9,w10,w11,w12,w13,w14,w0,w1,w2,w3,w4,w5,w6, o)
    #define AR8(o)  ASTEP(w8,w9,w10,w11,w12,w13,w14,w0,w1,w2,w3,w4,w5,w6,w7, o)
    #define AR9(o)  ASTEP(w9,w10,w11,w12,w13,w14,w0,w1,w2,w3,w4,w5,w6,w7,w8, o)
    #define AR10(o) ASTEP(w10,w11,w12,w13,w14,w0,w1,w2,w3,w4,w5,w6,w7,w8,w9, o)
    #define AR11(o) ASTEP(w11,w12,w13,w14,w0,w1,w2,w3,w4,w5,w6,w7,w8,w9,w10, o)
    #define AR12(o) ASTEP(w12,w13,w14,w0,w1,w2,w3,w4,w5,w6,w7,w8,w9,w10,w11, o)
    #define AR13(o) ASTEP(w13,w14,w0,w1,w2,w3,w4,w5,w6,w7,w8,w9,w10,w11,w12, o)
    #define AR14(o) ASTEP(w14,w0,w1,w2,w3,w4,w5,w6,w7,w8,w9,w10,w11,w12,w13, o)
    for (int mi = 0; mi < 2; ++mi) {            // 2*15 = 30 steps
        AR0(0) AR1(1) AR2(2) AR3(3) AR4(4) AR5(5) AR6(6) AR7(7)
        AR8(8) AR9(9) AR10(10) AR11(11) AR12(12) AR13(13) AR14(14)
        t += 15;
    }
    AR0(0) AR1(1) AR2(2)                        // 33 total
    #undef ASTEP
    __syncthreads();
    float* red = &rows[0][0];                   // reuse LDS: 256 x 17 floats
    int tid = threadIdx.x;
    red[tid*17+0]=a0;  red[tid*17+1]=a1;  red[tid*17+2]=a2;  red[tid*17+3]=a3;
    red[tid*17+4]=a4;  red[tid*17+5]=a5;  red[tid*17+6]=a6;  red[tid*17+7]=a7;
    red[tid*17+8]=a8;  red[tid*17+9]=a9;  red[tid*17+10]=a10; red[tid*17+11]=a11;
    red[tid*17+12]=a12; red[tid*17+13]=a13; red[tid*17+14]=a14; red[tid*17+15]=s1;
    __syncthreads();
    for (int off = 128; off > 0; off >>= 1) {
        if (tid < off)
            for (int k = 0; k < 16; ++k) red[tid*17+k] += red[(tid+off)*17+k];
        __syncthreads();
    }
    if (tid < 16) atomicAdd(&stats[tid], (double)red[tid]);
}

// ---------------- D2: boundary corrections — one stat per block ------------
__global__ __launch_bounds__(256) void k_edges(const float* __restrict__ zg, double* __restrict__ stats) {
    int v = blockIdx.x;                         // 0..146, uniform per block
    int mode, ia, ib;
    if (v < 105) { mode = 0; ia = v / 15; ib = ia + (v % 15); }          // head pair
    else if (v < 133) {
        int idx = v - 105; int i = 0, len = 7;
        while (idx >= len) { idx -= len; ++i; --len; }
        mode = 2; ia = i; ib = i + idx;                                   // tail-local idx
    }
    else if (v < 140) { mode = 1; ia = 0; ib = v - 133; }                 // prefix head
    else { mode = 3; ia = v - 140; ib = 6; }                              // suffix tail-local
    double acc = 0.0;
    for (int it = 0; it < 32; ++it) {
        int row = it * 256 + threadIdx.x;
        const float* zr = zg + (size_t)row * T_;
        float val;
        if (mode == 0)      val = zr[ia] * zr[ib];
        else if (mode == 2) val = zr[993 + ia] * zr[993 + ib];
        else if (mode == 1) { val = 0.f; for (int i = ia; i <= ib; ++i) val += zr[i]; }
        else                { val = 0.f; for (int i = ia; i <= ib; ++i) val += zr[993 + i]; }
        acc += (double)val;
    }
    __shared__ double red[256];
    red[threadIdx.x] = acc;
    __syncthreads();
    for (int off = 128; off > 0; off >>= 1) {
        if (threadIdx.x < off) red[threadIdx.x] += red[threadIdx.x + off];
        __syncthreads();
    }
    if (threadIdx.x == 0) stats[16 + v] = red[0];
}

// ---------------- E: finalize BN -> folded taps + shift --------------------
__global__ void k_finalize2(const double* __restrict__ stats, const float* __restrict__ conv_w,
                            const float* __restrict__ gamma, const float* __restrict__ beta,
                            float* __restrict__ scsh) {
    int h = threadIdx.x;
    if (h >= 16) return;
    const double M = (double)(B_ * N_) * (double)T_;
    double w[15];
    for (int k = 0; k < 15; ++k) w[k] = (double)conv_w[h * 15 + k];
    double SA = stats[15];
    const double* HP  = stats + 16;
    const double* TP  = stats + 16 + 105;
    const double* PRE = stats + 16 + 133;
    const double* SUF = stats + 16 + 140;
    double so = 0.0;
    for (int k = 0; k < 15; ++k) {
        double U = SA;
        if (k < 7)      U -= SUF[k];
        else if (k > 7) U -= PRE[k - 8];
        so += w[k] * U;
    }
    double mean_o = so / M;
    double q = 0.0;
    for (int k = 0; k < 15; ++k)
    for (int k2 = 0; k2 < 15; ++k2) {
        int a = (k < k2) ? k : k2;
        int d = (k < k2) ? (k2 - k) : (k - k2);
        double G = stats[d];
        if (a >= 8)
            for (int i = 0; i <= a - 8; ++i) G -= HP[i * 15 + d];
        if (a + d <= 6)
            for (int i = a + 993; i <= 999 - d; ++i) {
                int ip = i - 993;
                G -= TP[ip * 7 - ip * (ip - 1) / 2 + d];
            }
        q += w[k] * w[k2] * G;
    }
    double var = q / M - mean_o * mean_o;
    double sc = (double)gamma[h] / sqrt(var + 1e-5);
    scsh[240 + h] = (float)((double)beta[h] - mean_o * sc);
    for (int k = 0; k < 15; ++k) scsh[h * 15 + k] = (float)(w[k] * sc);
}

// ------- F: phase-split conv(+BN)+ELU (ILP-rich) then LIF scan (short) -----
// 16 rows x 16 ch per block; T in 21 chunks of 48 (last 40).
// LDS: in dbuf 2x16x68 f32 (8704 B) + act4 12x256 float4 (49152 B) = 57856 B.
__global__ __launch_bounds__(256, 2) void k_scan(const float* __restrict__ zg,
        const float* __restrict__ scsh, float* __restrict__ zfeat) {
    __shared__ float in_s[2][16][68];
    __shared__ float4 act4[12 * 256];
    int tid = threadIdx.x;
    int h = tid & 15, r = tid >> 4;
    int row0 = blockIdx.x * 16;
    float c0 = scsh[h*15+0],  c1 = scsh[h*15+1],  c2 = scsh[h*15+2],  c3 = scsh[h*15+3];
    float c4 = scsh[h*15+4],  c5 = scsh[h*15+5],  c6 = scsh[h*15+6],  c7 = scsh[h*15+7];
    float c8 = scsh[h*15+8],  c9 = scsh[h*15+9],  c10 = scsh[h*15+10], c11 = scsh[h*15+11];
    float c12 = scsh[h*15+12], c13 = scsh[h*15+13], c14 = scsh[h*15+14];
    float sh = scsh[240 + h];
    float v = 0.f, cnt = 0.f;

    #define STAGE(cc, db) { \
        int base = (cc) * 48 - 7; \
        for (int it = 0; it < 4; ++it) { \
            int idx = tid + it * 256; \
            int rr = idx >> 6, u = idx & 63; \
            int g = base + u; \
            float val = (g >= 0 && g < T_) ? zg[(size_t)(row0 + rr) * T_ + g] : 0.f; \
            in_s[db][rr][u] = val; \
        } }

    #define CONV15(x0,x1,x2,x3,x4,x5,x6,x7,x8,x9,xa,xb,xc,xd,xe) \
        (fmaf(c0,x0,fmaf(c3,x3,fmaf(c6,x6,fmaf(c9,x9,fmaf(c12,xc,sh))))) \
       + fmaf(c1,x1,fmaf(c4,x4,fmaf(c7,x7,fmaf(c10,xa,c13*xd)))) \
       + fmaf(c2,x2,fmaf(c5,x5,fmaf(c8,x8,fmaf(c11,xb,c14*xe)))))

    #define ELU1(zz) (fmaxf(zz,0.f) + __expf(fminf(zz,0.f)) - 1.f)

    #define GROUP(fa,fb,fc,fd,fe, gi) { \
        fe = in4r[(gi) + 4]; \
        float z0 = CONV15(fa.x,fa.y,fa.z,fa.w,fb.x,fb.y,fb.z,fb.w,fc.x,fc.y,fc.z,fc.w,fd.x,fd.y,fd.z); \
        float z1 = CONV15(fa.y,fa.z,fa.w,fb.x,fb.y,fb.z,fb.w,fc.x,fc.y,fc.z,fc.w,fd.x,fd.y,fd.z,fd.w); \
        float z2 = CONV15(fa.z,fa.w,fb.x,fb.y,fb.z,fb.w,fc.x,fc.y,fc.z,fc.w,fd.x,fd.y,fd.z,fd.w,fe.x); \
        float z3 = CONV15(fa.w,fb.x,fb.y,fb.z,fb.w,fc.x,fc.y,fc.z,fc.w,fd.x,fd.y,fd.z,fd.w,fe.x,fe.y); \
        act4[(gi) * 256 + tid] = float4{ELU1(z0), ELU1(z1), ELU1(z2), ELU1(z3)}; }

    #define LIF1(aa) { \
        v = fmaf(0.5f, v, aa); \
        float sp = (v > 0.5f) ? 1.f : 0.f; \
        cnt += sp; v = fmaf(-0.5f, sp, v); }
    #define LIF4(gi) { \
        float4 aa = act4[(gi) * 256 + tid]; \
        LIF1(aa.x) LIF1(aa.y) LIF1(aa.z) LIF1(aa.w) }

    STAGE(0, 0)
    __syncthreads();
    int buf = 0;
    #pragma unroll 1
    for (int c = 0; c < 20; ++c) {
        STAGE(c + 1, buf ^ 1)                    // async prefetch next chunk
        const float4* in4r = (const float4*)&in_s[buf][r][0];
        float4 f0 = in4r[0], f1 = in4r[1], f2 = in4r[2], f3 = in4r[3], f4;
        GROUP(f0,f1,f2,f3,f4, 0)  GROUP(f1,f2,f3,f4,f0, 1)  GROUP(f2,f3,f4,f0,f1, 2)
        GROUP(f3,f4,f0,f1,f2, 3)  GROUP(f4,f0,f1,f2,f3, 4)  GROUP(f0,f1,f2,f3,f4, 5)
        GROUP(f1,f2,f3,f4,f0, 6)  GROUP(f2,f3,f4,f0,f1, 7)  GROUP(f3,f4,f0,f1,f2, 8)
        GROUP(f4,f0,f1,f2,f3, 9)  GROUP(f0,f1,f2,f3,f4, 10) GROUP(f1,f2,f3,f4,f0, 11)
        LIF4(0) LIF4(1) LIF4(2) LIF4(3) LIF4(4) LIF4(5)
        LIF4(6) LIF4(7) LIF4(8) LIF4(9) LIF4(10) LIF4(11)
        __syncthreads();
        buf ^= 1;
    }
    {   // tail chunk c=20: 40 outputs = 10 groups
        const float4* in4r = (const float4*)&in_s[buf][r][0];
        float4 f0 = in4r[0], f1 = in4r[1], f2 = in4r[2], f3 = in4r[3], f4;
        GROUP(f0,f1,f2,f3,f4, 0)  GROUP(f1,f2,f3,f4,f0, 1)  GROUP(f2,f3,f4,f0,f1, 2)
        GROUP(f3,f4,f0,f1,f2, 3)  GROUP(f4,f0,f1,f2,f3, 4)  GROUP(f0,f1,f2,f3,f4, 5)
        GROUP(f1,f2,f3,f4,f0, 6)  GROUP(f2,f3,f4,f0,f1, 7)  GROUP(f3,f4,f0,f1,f2, 8)
        GROUP(f4,f0,f1,f2,f3, 9)
        LIF4(0) LIF4(1) LIF4(2) LIF4(3) LIF4(4)
        LIF4(5) LIF4(6) LIF4(7) LIF4(8) LIF4(9)
    }
    #undef STAGE
    #undef CONV15
    #undef ELU1
    #undef GROUP
    #undef LIF1
    #undef LIF4
    int row = row0 + r;
    int b = row >> 6, i = row & 63;
    zfeat[(size_t)b * 1024 + h * 64 + i] = cnt * (1.0f / (float)T_);
}

// ---------------- G: logits = z_feat @ fc_w.T + fc_b -----------------------
__global__ __launch_bounds__(256) void k_fc(const float* __restrict__ zfeat, const float* __restrict__ fc_w,
                     const float* __restrict__ fc_b, float* __restrict__ logits) {
    int b = blockIdx.x;
    const float* zf = zfeat + (size_t)b * 1024;
    float a0 = 0.f, a1 = 0.f, a2 = 0.f, a3 = 0.f;
    for (int f = threadIdx.x; f < 1024; f += 256) {
        float z = zf[f];
        a0 += z * fc_w[f];
        a1 += z * fc_w[1024 + f];
        a2 += z * fc_w[2048 + f];
        a3 += z * fc_w[3072 + f];
    }
    __shared__ float red[4][256];
    red[0][threadIdx.x] = a0; red[1][threadIdx.x] = a1;
    red[2][threadIdx.x] = a2; red[3][threadIdx.x] = a3;
    __syncthreads();
    for (int off = 128; off > 0; off >>= 1) {
        if (threadIdx.x < off) {
            red[0][threadIdx.x] += red[0][threadIdx.x + off];
            red[1][threadIdx.x] += red[1][threadIdx.x + off];
            red[2][threadIdx.x] += red[2][threadIdx.x + off];
            red[3][threadIdx.x] += red[3][threadIdx.x + off];
        }
        __syncthreads();
    }
    if (threadIdx.x < 4) logits[b * 4 + threadIdx.x] = red[threadIdx.x][0] + fc_b[threadIdx.x];
}

extern "C" void kernel_launch(void* const* d_in, const int* in_sizes, int n_in,
                              void* d_out, int out_size, void* d_ws, size_t ws_size,
                              hipStream_t stream) {
    (void)in_sizes; (void)n_in; (void)out_size; (void)ws_size;
    const float* x      = (const float*)d_in[0];
    const float* q_w    = (const float*)d_in[1];
    const float* q_b    = (const float*)d_in[2];
    const float* k_w    = (const float*)d_in[3];
    const float* k_b    = (const float*)d_in[4];
    const float* conv_w = (const float*)d_in[5];
    const float* bn_g   = (const float*)d_in[7];
    const float* bn_b   = (const float*)d_in[8];
    const float* fc_w   = (const float*)d_in[9];
    const float* fc_b   = (const float*)d_in[10];

    float* out    = (float*)d_out;
    float* logits = out;                        // 128*4
    float* zfeat  = out + 512;                  // 128*1024
    float* wmat   = out + 512 + 131072;         // 128*64*64

    char* ws      = (char*)d_ws;
    float* energy = (float*)ws;                               // 8192 f32
    float* zg     = (float*)(ws + 32768);                     // 8.192M f32
    double* stats = (double*)(ws + 32768 + 32768000);         // 163 f64
    float* scsh   = (float*)(ws + 32768 + 32768000 + 2048);   // 256 f32

    k_energy<<<B_ * N_, 256, 0, stream>>>(x, energy);
    k_attn_softmax<<<B_ * N_, 64, 0, stream>>>(energy, q_w, q_b, k_w, k_b, wmat);
    k_zgcn<<<dim3(8, B_), 256, 0, stream>>>(wmat, x, zg);
    hipMemsetAsync(stats, 0, 163 * sizeof(double), stream);
    k_autocorr<<<B_ * N_ / 8, 256, 0, stream>>>(zg, stats);
    k_edges<<<147, 256, 0, stream>>>(zg, stats);
    k_finalize2<<<1, 64, 0, stream>>>(stats, conv_w, bn_g, bn_b, scsh);
    k_scan<<<B_ * N_ / 16, 256, 0, stream>>>(zg, scsh, zfeat);
    k_fc<<<B_, 256, 0, stream>>>(zfeat, fc_w, fc_b, logits);
}

// Round 9
// 239.303 us; speedup vs baseline: 1.1614x; 1.0374x over previous
//
#include <hip/hip_runtime.h>

#define B_ 128
#define N_ 64
#define T_ 1000
#define H_ 16

// ---------------- A: energy[b,i] = var(x[b,0,i,:], ddof=1) ----------------
__global__ __launch_bounds__(256) void k_energy(const float* __restrict__ x, float* __restrict__ energy) {
    int row = blockIdx.x;                       // b*64 + i
    const float* xr = x + (size_t)row * T_;
    float s = 0.f, s2 = 0.f;
    for (int t4 = threadIdx.x; t4 < 250; t4 += 256) {
        float4 v = ((const float4*)xr)[t4];
        s += v.x + v.y + v.z + v.w;
        s2 += v.x*v.x + v.y*v.y + v.z*v.z + v.w*v.w;
    }
    __shared__ float r1[256], r2[256];
    r1[threadIdx.x] = s; r2[threadIdx.x] = s2;
    __syncthreads();
    for (int off = 128; off > 0; off >>= 1) {
        if (threadIdx.x < off) {
            r1[threadIdx.x] += r1[threadIdx.x + off];
            r2[threadIdx.x] += r2[threadIdx.x + off];
        }
        __syncthreads();
    }
    if (threadIdx.x == 0) {
        float S = r1[0], S2 = r2[0];
        energy[row] = (S2 - S * S / (float)T_) / (float)(T_ - 1);
    }
}

// ---------------- B: attn + diag-mask + softmax -> w (written to d_out) ----
__global__ void k_attn_softmax(const float* __restrict__ energy,
                               const float* __restrict__ q_w, const float* __restrict__ q_b,
                               const float* __restrict__ k_w, const float* __restrict__ k_b,
                               float* __restrict__ wout) {
    int row = blockIdx.x;                       // b*64 + i
    int b = row >> 6, i = row & 63;
    int j = threadIdx.x;                        // 64 threads
    float ei = energy[b * 64 + i];
    float ej = energy[b * 64 + j];
    float a = 0.f;
    #pragma unroll
    for (int h = 0; h < H_; ++h)
        a += (ei * q_w[h] + q_b[h]) * (ej * k_w[h] + k_b[h]);
    a *= 0.25f;                                 // H^(-1/2), H=16
    if (j == i) a = -1e9f;
    float m = a;
    #pragma unroll
    for (int mask = 32; mask; mask >>= 1) m = fmaxf(m, __shfl_xor(m, mask));
    float p = __expf(a - m);
    float s = p;
    #pragma unroll
    for (int mask = 32; mask; mask >>= 1) s += __shfl_xor(s, mask);
    wout[(size_t)row * 64 + j] = p / s;
}

// ---------------- C: z_gcn = w @ xs + x  (register-tiled 8x4) --------------
#define ZTC 128
__global__ __launch_bounds__(256) void k_zgcn(const float* __restrict__ wmat,
        const float* __restrict__ x, float* __restrict__ zg) {
    int b = blockIdx.y;
    int t0 = blockIdx.x * ZTC;                  // 8 chunks: 0,128,...,896
    __shared__ __attribute__((aligned(16))) float wsh[64 * 64];
    __shared__ __attribute__((aligned(16))) float xs[64][ZTC];
    const float4* wb4 = (const float4*)(wmat + (size_t)b * 4096);
    float4* wsh4 = (float4*)wsh;
    for (int i = threadIdx.x; i < 1024; i += 256) wsh4[i] = wb4[i];
    const float* xb = x + (size_t)b * 64 * T_;
    for (int i = threadIdx.x; i < 2048; i += 256) {
        int jj = i >> 5;                        // row (32 float4 per row)
        int c4 = i & 31;
        int tt = t0 + c4 * 4;
        float4 val;
        if (tt + 3 < T_) val = *(const float4*)(xb + jj * T_ + tt);
        else {
            val.x = (tt     < T_) ? xb[jj * T_ + tt]     : 0.f;
            val.y = (tt + 1 < T_) ? xb[jj * T_ + tt + 1] : 0.f;
            val.z = (tt + 2 < T_) ? xb[jj * T_ + tt + 2] : 0.f;
            val.w = (tt + 3 < T_) ? xb[jj * T_ + tt + 3] : 0.f;
        }
        *(float4*)&xs[jj][c4 * 4] = val;
    }
    __syncthreads();
    int gi = threadIdx.x >> 5;                  // 8 ii-groups
    int gt = threadIdx.x & 31;                  // 32 tt-groups
    int ii0 = gi * 8, tt0 = gt * 4;
    float4 acc[8];
    #pragma unroll
    for (int r = 0; r < 8; ++r) acc[r] = float4{0.f, 0.f, 0.f, 0.f};
    for (int jj = 0; jj < 64; ++jj) {
        float4 xv = *(const float4*)&xs[jj][tt0];
        #pragma unroll
        for (int r = 0; r < 8; ++r) {
            float wv = wsh[(ii0 + r) * 64 + jj];
            acc[r].x += wv * xv.x; acc[r].y += wv * xv.y;
            acc[r].z += wv * xv.z; acc[r].w += wv * xv.w;
        }
    }
    int tt = t0 + tt0;
    #pragma unroll
    for (int r = 0; r < 8; ++r) {
        float4 res = *(const float4*)&xs[ii0 + r][tt0];
        acc[r].x += res.x; acc[r].y += res.y; acc[r].z += res.z; acc[r].w += res.w;
        float* dst = zg + (size_t)b * 64 * T_ + (size_t)(ii0 + r) * T_;
        if (tt + 3 < T_) {
            *(float4*)(dst + tt) = acc[r];
        } else {
            if (tt     < T_) dst[tt]     = acc[r].x;
            if (tt + 1 < T_) dst[tt + 1] = acc[r].y;
            if (tt + 2 < T_) dst[tt + 2] = acc[r].z;
            if (tt + 3 < T_) dst[tt + 3] = acc[r].w;
        }
    }
}

// ---------------- D1: autocorr lags 0..14 + total sum (LDS-staged) --------
// stats[0..14] = A[d] = sum_rows sum_t z[t]*z[t+d];  stats[15] = SA = sum z
// block: 256 threads = 8 rows x 32 spans of 33; LDS zero-padded past T.
__global__ __launch_bounds__(256) void k_autocorr(const float* __restrict__ zg, double* __restrict__ stats) {
    __shared__ float rows[8][1070];             // 34240 B; stride-33 spans, conflict-free
    int row0 = blockIdx.x * 8;
    for (int idx = threadIdx.x; idx < 8 * 1070; idx += 256) {
        int rr = idx / 1070, j = idx - rr * 1070;
        rows[rr][j] = (j < T_) ? zg[(size_t)(row0 + rr) * T_ + j] : 0.f;
    }
    __syncthreads();
    int r = threadIdx.x >> 5, q = threadIdx.x & 31;
    const float* p = &rows[r][0];
    int t = q * 33;                             // spans cover 0..1055 >= 1000, zero-padded
    float w0=p[t+0], w1=p[t+1], w2=p[t+2], w3=p[t+3], w4=p[t+4], w5=p[t+5], w6=p[t+6],
          w7=p[t+7], w8=p[t+8], w9=p[t+9], w10=p[t+10], w11=p[t+11], w12=p[t+12], w13=p[t+13], w14;
    float a0=0.f,a1=0.f,a2=0.f,a3=0.f,a4=0.f,a5=0.f,a6=0.f,a7=0.f,a8=0.f,a9=0.f,
          a10=0.f,a11=0.f,a12=0.f,a13=0.f,a14=0.f, s1=0.f;
    #define ASTEP(wA,wB,wC,wD,wE,wF,wG,wH,wI,wJ,wK,wL,wM,wN,wO, off) { \
        wO = p[t + (off) + 14]; \
        s1 += wA; \
        a0  = fmaf(wA,wA,a0);  a1  = fmaf(wA,wB,a1);  a2  = fmaf(wA,wC,a2);  \
        a3  = fmaf(wA,wD,a3);  a4  = fmaf(wA,wE,a4);  a5  = fmaf(wA,wF,a5);  \
        a6  = fmaf(wA,wG,a6);  a7  = fmaf(wA,wH,a7);  a8  = fmaf(wA,wI,a8);  \
        a9  = fmaf(wA,wJ,a9);  a10 = fmaf(wA,wK,a10); a11 = fmaf(wA,wL,a11); \
        a12 = fmaf(wA,wM,a12); a13 = fmaf(wA,wN,a13); a14 = fmaf(wA,wO,a14); }
    #define AR0(o)  ASTEP(w0,w1,w2,w3,w4,w5,w6,w7,w8,w9,w10,w11,w12,w13,w14, o)
    #define AR1(o)  ASTEP(w1,w2,w3,w4,w5,w6,w7,w8,w9,w10,w11,w12,w13,w14,w0, o)
    #define AR2(o)  ASTEP(w2,w3,w4,w5,w6,w7,w8,w9,w10,w11,w12,w13,w14,w0,w1, o)
    #define AR3(o)  ASTEP(w3,w4,w5,w6,w7,w8,w9,w10,w11,w12,w13,w14,w0,w1,w2, o)
    #define AR4(o)  ASTEP(w4,w5,w6,w7,w8,w9,w10,w11,w12,w13,w14,w0,w1,w2,w3, o)
    #define AR5(o)  ASTEP(w5,w6,w7,w8,w9,w10,w11,w12,w13,w14,w0,w1,w2,w3,w4, o)
    #define AR6(o)  ASTEP(w6,w7,w8,w9,w10,w11,w12,w13,w14,w0,w1,w2,w3,w4,w5, o)
    #define AR7(o)  ASTEP(w7,w8,w9,w10,w11,w12,w13,w14,w0,w1,w2,w3,w4,w5,w6, o)
    #define AR8(o)  ASTEP(w8,w9,w10,w11,w12,w13,w14,w0,w1,w2,w3,w4,w5,w6,w7, o)
    #define AR9(o)  ASTEP(w9,w10,w11,w12,w13,w14,w0,w1,w2,w3,w4,w5,w6,w7,w8, o)
    #define AR10(o) ASTEP(w10,w11,w12,w13,w14,w0,w1,w2,w3,w4,w5,w6,w7,w8,w9, o)
    #define AR11(o) ASTEP(w11,w12,w13,w14,w0,w1,w2,w3,w4,w5,w6,w7,w8,w9,w10, o)
    #define AR12(o) ASTEP(w12,w13,w14,w0,w1,w2,w3,w4,w5,w6,w7,w8,w9,w10,w11, o)
    #define AR13(o) ASTEP(w13,w14,w0,w1,w2,w3,w4,w5,w6,w7,w8,w9,w10,w11,w12, o)
    #define AR14(o) ASTEP(w14,w0,w1,w2,w3,w4,w5,w6,w7,w8,w9,w10,w11,w12,w13, o)
    for (int mi = 0; mi < 2; ++mi) {            // 2*15 = 30 steps
        AR0(0) AR1(1) AR2(2) AR3(3) AR4(4) AR5(5) AR6(6) AR7(7)
        AR8(8) AR9(9) AR10(10) AR11(11) AR12(12) AR13(13) AR14(14)
        t += 15;
    }
    AR0(0) AR1(1) AR2(2)                        // 33 total
    #undef ASTEP
    __syncthreads();
    float* red = &rows[0][0];                   // reuse LDS: 256 x 17 floats
    int tid = threadIdx.x;
    red[tid*17+0]=a0;  red[tid*17+1]=a1;  red[tid*17+2]=a2;  red[tid*17+3]=a3;
    red[tid*17+4]=a4;  red[tid*17+5]=a5;  red[tid*17+6]=a6;  red[tid*17+7]=a7;
    red[tid*17+8]=a8;  red[tid*17+9]=a9;  red[tid*17+10]=a10; red[tid*17+11]=a11;
    red[tid*17+12]=a12; red[tid*17+13]=a13; red[tid*17+14]=a14; red[tid*17+15]=s1;
    __syncthreads();
    for (int off = 128; off > 0; off >>= 1) {
        if (tid < off)
            for (int k = 0; k < 16; ++k) red[tid*17+k] += red[(tid+off)*17+k];
        __syncthreads();
    }
    if (tid < 16) atomicAdd(&stats[tid], (double)red[tid]);
}

// ---------------- D2: boundary corrections — one stat per block ------------
__global__ __launch_bounds__(256) void k_edges(const float* __restrict__ zg, double* __restrict__ stats) {
    int v = blockIdx.x;                         // 0..146, uniform per block
    int mode, ia, ib;
    if (v < 105) { mode = 0; ia = v / 15; ib = ia + (v % 15); }          // head pair
    else if (v < 133) {
        int idx = v - 105; int i = 0, len = 7;
        while (idx >= len) { idx -= len; ++i; --len; }
        mode = 2; ia = i; ib = i + idx;                                   // tail-local idx
    }
    else if (v < 140) { mode = 1; ia = 0; ib = v - 133; }                 // prefix head
    else { mode = 3; ia = v - 140; ib = 6; }                              // suffix tail-local
    double acc = 0.0;
    for (int it = 0; it < 32; ++it) {
        int row = it * 256 + threadIdx.x;
        const float* zr = zg + (size_t)row * T_;
        float val;
        if (mode == 0)      val = zr[ia] * zr[ib];
        else if (mode == 2) val = zr[993 + ia] * zr[993 + ib];
        else if (mode == 1) { val = 0.f; for (int i = ia; i <= ib; ++i) val += zr[i]; }
        else                { val = 0.f; for (int i = ia; i <= ib; ++i) val += zr[993 + i]; }
        acc += (double)val;
    }
    __shared__ double red[256];
    red[threadIdx.x] = acc;
    __syncthreads();
    for (int off = 128; off > 0; off >>= 1) {
        if (threadIdx.x < off) red[threadIdx.x] += red[threadIdx.x + off];
        __syncthreads();
    }
    if (threadIdx.x == 0) stats[16 + v] = red[0];
}

// ---------------- E: finalize BN -> folded taps + shift --------------------
__global__ void k_finalize2(const double* __restrict__ stats, const float* __restrict__ conv_w,
                            const float* __restrict__ gamma, const float* __restrict__ beta,
                            float* __restrict__ scsh) {
    int h = threadIdx.x;
    if (h >= 16) return;
    const double M = (double)(B_ * N_) * (double)T_;
    double w[15];
    for (int k = 0; k < 15; ++k) w[k] = (double)conv_w[h * 15 + k];
    double SA = stats[15];
    const double* HP  = stats + 16;
    const double* TP  = stats + 16 + 105;
    const double* PRE = stats + 16 + 133;
    const double* SUF = stats + 16 + 140;
    double so = 0.0;
    for (int k = 0; k < 15; ++k) {
        double U = SA;
        if (k < 7)      U -= SUF[k];
        else if (k > 7) U -= PRE[k - 8];
        so += w[k] * U;
    }
    double mean_o = so / M;
    double q = 0.0;
    for (int k = 0; k < 15; ++k)
    for (int k2 = 0; k2 < 15; ++k2) {
        int a = (k < k2) ? k : k2;
        int d = (k < k2) ? (k2 - k) : (k - k2);
        double G = stats[d];
        if (a >= 8)
            for (int i = 0; i <= a - 8; ++i) G -= HP[i * 15 + d];
        if (a + d <= 6)
            for (int i = a + 993; i <= 999 - d; ++i) {
                int ip = i - 993;
                G -= TP[ip * 7 - ip * (ip - 1) / 2 + d];
            }
        q += w[k] * w[k2] * G;
    }
    double var = q / M - mean_o * mean_o;
    double sc = (double)gamma[h] / sqrt(var + 1e-5);
    scsh[240 + h] = (float)((double)beta[h] - mean_o * sc);
    for (int k = 0; k < 15; ++k) scsh[h * 15 + k] = (float)(w[k] * sc);
}

// ------- F: conv(+BN)+ELU with acts in REGISTERS, then LIF; T14 staging ----
// 16 rows x 16 ch per block; T in 21 chunks of 48 (last 40).
// LDS: in dbuf 2x16x68 f32 = 8704 B only. Acts live in 12 named float4 regs.
__global__ __launch_bounds__(256) void k_scan(const float* __restrict__ zg,
        const float* __restrict__ scsh, float* __restrict__ zfeat) {
    __shared__ float in_s[2][16][68];
    int tid = threadIdx.x;
    int h = tid & 15, r = tid >> 4;
    int row0 = blockIdx.x * 16;
    float c0 = scsh[h*15+0],  c1 = scsh[h*15+1],  c2 = scsh[h*15+2],  c3 = scsh[h*15+3];
    float c4 = scsh[h*15+4],  c5 = scsh[h*15+5],  c6 = scsh[h*15+6],  c7 = scsh[h*15+7];
    float c8 = scsh[h*15+8],  c9 = scsh[h*15+9],  c10 = scsh[h*15+10], c11 = scsh[h*15+11];
    float c12 = scsh[h*15+12], c13 = scsh[h*15+13], c14 = scsh[h*15+14];
    float sh = scsh[240 + h];
    float v = 0.f, cnt = 0.f;
    float ld0, ld1, ld2, ld3;
    int su = tid & 63, sr = tid >> 6;           // stage coords: 4 rows apart

    #define STAGE_LOAD(cc) { \
        int g = (cc) * 48 - 7 + su; \
        bool ok = (g >= 0 && g < T_); \
        const float* zp = zg + (size_t)(row0 + sr) * T_ + g; \
        ld0 = ok ? zp[0] : 0.f; \
        ld1 = ok ? zp[4 * T_] : 0.f; \
        ld2 = ok ? zp[8 * T_] : 0.f; \
        ld3 = ok ? zp[12 * T_] : 0.f; }

    #define STAGE_WRITE(db) { \
        in_s[db][sr][su]      = ld0; \
        in_s[db][sr + 4][su]  = ld1; \
        in_s[db][sr + 8][su]  = ld2; \
        in_s[db][sr + 12][su] = ld3; }

    #define CONV15(x0,x1,x2,x3,x4,x5,x6,x7,x8,x9,xa,xb,xc,xd,xe) \
        (fmaf(c0,x0,fmaf(c3,x3,fmaf(c6,x6,fmaf(c9,x9,fmaf(c12,xc,sh))))) \
       + fmaf(c1,x1,fmaf(c4,x4,fmaf(c7,x7,fmaf(c10,xa,c13*xd)))) \
       + fmaf(c2,x2,fmaf(c5,x5,fmaf(c8,x8,fmaf(c11,xb,c14*xe)))))

    #define ELU1(zz) (fmaxf(zz,0.f) + __expf(fminf(zz,0.f)) - 1.f)

    #define GROUP(fa,fb,fc,fd,fe, gi, dst) { \
        fe = in4r[(gi) + 4]; \
        float z0 = CONV15(fa.x,fa.y,fa.z,fa.w,fb.x,fb.y,fb.z,fb.w,fc.x,fc.y,fc.z,fc.w,fd.x,fd.y,fd.z); \
        float z1 = CONV15(fa.y,fa.z,fa.w,fb.x,fb.y,fb.z,fb.w,fc.x,fc.y,fc.z,fc.w,fd.x,fd.y,fd.z,fd.w); \
        float z2 = CONV15(fa.z,fa.w,fb.x,fb.y,fb.z,fb.w,fc.x,fc.y,fc.z,fc.w,fd.x,fd.y,fd.z,fd.w,fe.x); \
        float z3 = CONV15(fa.w,fb.x,fb.y,fb.z,fb.w,fc.x,fc.y,fc.z,fc.w,fd.x,fd.y,fd.z,fd.w,fe.x,fe.y); \
        dst = float4{ELU1(z0), ELU1(z1), ELU1(z2), ELU1(z3)}; }

    #define LIF1(aa) { \
        v = fmaf(0.5f, v, aa); \
        float sp = (v > 0.5f) ? 1.f : 0.f; \
        cnt += sp; v = fmaf(-0.5f, sp, v); }
    #define LIF4(av) { LIF1(av.x) LIF1(av.y) LIF1(av.z) LIF1(av.w) }

    STAGE_LOAD(0)
    STAGE_WRITE(0)
    __syncthreads();
    int buf = 0;
    #pragma unroll 1
    for (int c = 0; c < 20; ++c) {
        STAGE_LOAD(c + 1)                        // issue early (T14)
        const float4* in4r = (const float4*)&in_s[buf][r][0];
        float4 a0,a1,a2,a3,a4,a5,a6,a7,a8,a9,aA,aB;
        float4 f0 = in4r[0], f1 = in4r[1], f2 = in4r[2], f3 = in4r[3], f4;
        GROUP(f0,f1,f2,f3,f4, 0, a0)  GROUP(f1,f2,f3,f4,f0, 1, a1)  GROUP(f2,f3,f4,f0,f1, 2, a2)
        GROUP(f3,f4,f0,f1,f2, 3, a3)  GROUP(f4,f0,f1,f2,f3, 4, a4)  GROUP(f0,f1,f2,f3,f4, 5, a5)
        GROUP(f1,f2,f3,f4,f0, 6, a6)  GROUP(f2,f3,f4,f0,f1, 7, a7)  GROUP(f3,f4,f0,f1,f2, 8, a8)
        GROUP(f4,f0,f1,f2,f3, 9, a9)  GROUP(f0,f1,f2,f3,f4, 10, aA) GROUP(f1,f2,f3,f4,f0, 11, aB)
        LIF4(a0) LIF4(a1) LIF4(a2) LIF4(a3) LIF4(a4) LIF4(a5)
        LIF4(a6) LIF4(a7) LIF4(a8) LIF4(a9) LIF4(aA) LIF4(aB)
        STAGE_WRITE(buf ^ 1)                     // write late (after compute)
        __syncthreads();
        buf ^= 1;
    }
    {   // tail chunk c=20: 40 outputs = 10 groups
        const float4* in4r = (const float4*)&in_s[buf][r][0];
        float4 a0,a1,a2,a3,a4,a5,a6,a7,a8,a9;
        float4 f0 = in4r[0], f1 = in4r[1], f2 = in4r[2], f3 = in4r[3], f4;
        GROUP(f0,f1,f2,f3,f4, 0, a0)  GROUP(f1,f2,f3,f4,f0, 1, a1)  GROUP(f2,f3,f4,f0,f1, 2, a2)
        GROUP(f3,f4,f0,f1,f2, 3, a3)  GROUP(f4,f0,f1,f2,f3, 4, a4)  GROUP(f0,f1,f2,f3,f4, 5, a5)
        GROUP(f1,f2,f3,f4,f0, 6, a6)  GROUP(f2,f3,f4,f0,f1, 7, a7)  GROUP(f3,f4,f0,f1,f2, 8, a8)
        GROUP(f4,f0,f1,f2,f3, 9, a9)
        LIF4(a0) LIF4(a1) LIF4(a2) LIF4(a3) LIF4(a4)
        LIF4(a5) LIF4(a6) LIF4(a7) LIF4(a8) LIF4(a9)
    }
    #undef STAGE_LOAD
    #undef STAGE_WRITE
    #undef CONV15
    #undef ELU1
    #undef GROUP
    #undef LIF1
    #undef LIF4
    int row = row0 + r;
    int b = row >> 6, i = row & 63;
    zfeat[(size_t)b * 1024 + h * 64 + i] = cnt * (1.0f / (float)T_);
}

// ---------------- G: logits = z_feat @ fc_w.T + fc_b -----------------------
__global__ __launch_bounds__(256) void k_fc(const float* __restrict__ zfeat, const float* __restrict__ fc_w,
                     const float* __restrict__ fc_b, float* __restrict__ logits) {
    int b = blockIdx.x;
    const float* zf = zfeat + (size_t)b * 1024;
    float a0 = 0.f, a1 = 0.f, a2 = 0.f, a3 = 0.f;
    for (int f = threadIdx.x; f < 1024; f += 256) {
        float z = zf[f];
        a0 += z * fc_w[f];
        a1 += z * fc_w[1024 + f];
        a2 += z * fc_w[2048 + f];
        a3 += z * fc_w[3072 + f];
    }
    __shared__ float red[4][256];
    red[0][threadIdx.x] = a0; red[1][threadIdx.x] = a1;
    red[2][threadIdx.x] = a2; red[3][threadIdx.x] = a3;
    __syncthreads();
    for (int off = 128; off > 0; off >>= 1) {
        if (threadIdx.x < off) {
            red[0][threadIdx.x] += red[0][threadIdx.x + off];
            red[1][threadIdx.x] += red[1][threadIdx.x + off];
            red[2][threadIdx.x] += red[2][threadIdx.x + off];
            red[3][threadIdx.x] += red[3][threadIdx.x + off];
        }
        __syncthreads();
    }
    if (threadIdx.x < 4) logits[b * 4 + threadIdx.x] = red[threadIdx.x][0] + fc_b[threadIdx.x];
}

extern "C" void kernel_launch(void* const* d_in, const int* in_sizes, int n_in,
                              void* d_out, int out_size, void* d_ws, size_t ws_size,
                              hipStream_t stream) {
    (void)in_sizes; (void)n_in; (void)out_size; (void)ws_size;
    const float* x      = (const float*)d_in[0];
    const float* q_w    = (const float*)d_in[1];
    const float* q_b    = (const float*)d_in[2];
    const float* k_w    = (const float*)d_in[3];
    const float* k_b    = (const float*)d_in[4];
    const float* conv_w = (const float*)d_in[5];
    const float* bn_g   = (const float*)d_in[7];
    const float* bn_b   = (const float*)d_in[8];
    const float* fc_w   = (const float*)d_in[9];
    const float* fc_b   = (const float*)d_in[10];

    float* out    = (float*)d_out;
    float* logits = out;                        // 128*4
    float* zfeat  = out + 512;                  // 128*1024
    float* wmat   = out + 512 + 131072;         // 128*64*64

    char* ws      = (char*)d_ws;
    float* energy = (float*)ws;                               // 8192 f32
    float* zg     = (float*)(ws + 32768);                     // 8.192M f32
    double* stats = (double*)(ws + 32768 + 32768000);         // 163 f64
    float* scsh   = (float*)(ws + 32768 + 32768000 + 2048);   // 256 f32

    k_energy<<<B_ * N_, 256, 0, stream>>>(x, energy);
    k_attn_softmax<<<B_ * N_, 64, 0, stream>>>(energy, q_w, q_b, k_w, k_b, wmat);
    k_zgcn<<<dim3(8, B_), 256, 0, stream>>>(wmat, x, zg);
    hipMemsetAsync(stats, 0, 163 * sizeof(double), stream);
    k_autocorr<<<B_ * N_ / 8, 256, 0, stream>>>(zg, stats);
    k_edges<<<147, 256, 0, stream>>>(zg, stats);
    k_finalize2<<<1, 64, 0, stream>>>(stats, conv_w, bn_g, bn_b, scsh);
    k_scan<<<B_ * N_ / 16, 256, 0, stream>>>(zg, scsh, zfeat);
    k_fc<<<B_, 256, 0, stream>>>(zfeat, fc_w, fc_b, logits);
}